// Round 11
// baseline (533.636 us; speedup 1.0000x reference)
//
#include <hip/hip_runtime.h>
#include <math.h>

#define NN 50000
#define EE 800000
#define GG 512
#define HH 128
#define LL 3
#define OUTC 10
#define THR 0.01f

typedef unsigned short u16;
typedef unsigned int u32;
typedef __attribute__((ext_vector_type(8))) short short8;
typedef __attribute__((ext_vector_type(4))) float f32x4;

__device__ __forceinline__ float elu_f(float x){ return x > 0.f ? x : (expf(x)-1.f); }
__device__ __forceinline__ u16 f2bf(float f){
    u32 u = __float_as_uint(f);
    return (u16)((u + 0x7fffu + ((u>>16)&1u)) >> 16);
}
__device__ __forceinline__ float bf2f(u16 b){ return __uint_as_float(((u32)b)<<16); }
__device__ __forceinline__ u32 pack2(float a, float b){
    return (u32)f2bf(a) | ((u32)f2bf(b)<<16);
}

// ---------------- setup kernels ----------------

__device__ void softmax_row(const float* in, float* out, int c){
    float m = in[0];
    for (int j=1;j<c;++j) m = fmaxf(m, in[j]);
    float s = 0.f;
    for (int j=0;j<c;++j){ float e = expf(in[j]-m); out[j]=e; s+=e; }
    for (int j=0;j<c;++j) out[j] /= s;
}

// coef layout: na[12] @0, pool[9] @12, ro[12] @21, la[3] @33
__global__ void prep_coef_k(const float* __restrict__ na, const float* __restrict__ pl,
                            const float* __restrict__ ro, const float* __restrict__ la,
                            float* __restrict__ coef){
    if (threadIdx.x != 0 || blockIdx.x != 0) return;
    for (int i=0;i<LL;++i)   softmax_row(na + i*4, coef + i*4, 4);
    for (int i=0;i<LL;++i)   softmax_row(pl + i*3, coef + 12 + i*3, 3);
    for (int i=0;i<LL+1;++i) softmax_row(ro + i*3, coef + 21 + i*3, 3);
    softmax_row(la, coef + 33, 3);
}

// Per-layer combined B stacks, bf16, TRANSPOSED to [n][k]:
// B0 = a1*W2+a2*W3+a3*W4 (h), B1 = a2*W3+a3*W5 (sagg), B2 = a1*W1 (sagg*invdeg), B3 = a0*W0 (gagg)
__global__ __launch_bounds__(256) void prep_w_k(const float* __restrict__ gW,
                                                const float* __restrict__ lin1W,
                                                const float* __restrict__ coef,
                                                u16* __restrict__ Wc, u16* __restrict__ lin1t){
    int idx = blockIdx.x*256 + threadIdx.x;
    const int total = LL*4*16384;
    if (idx < total){
        int i = idx >> 16;
        int rem = idx & 65535;
        int p = rem >> 14;
        int j = rem & 16383;
        int n = j >> 7, k = j & 127;
        const float* W = gW + (size_t)i*6*16384;
        float a0=coef[i*4], a1=coef[i*4+1], a2=coef[i*4+2], a3=coef[i*4+3];
        int e = k*128 + n;
        float v;
        if (p==0)      v = a1*W[2*16384+e] + a2*W[3*16384+e] + a3*W[4*16384+e];
        else if (p==1) v = a2*W[3*16384+e] + a3*W[5*16384+e];
        else if (p==2) v = a1*W[1*16384+e];
        else           v = a0*W[0*16384+e];
        Wc[(size_t)(i*4+p)*16384 + n*128 + k] = f2bf(v);
    } else if (idx < total + 16384){
        int j = idx - total;
        int n = j >> 7, k = j & 127;
        lin1t[n*128 + k] = f2bf(lin1W[k*128 + n]);
    }
}

__global__ void x2bf_k(const float* __restrict__ x, u16* __restrict__ xb){
    int i = blockIdx.x*256 + threadIdx.x;
    if (i >= NN*HH/8) return;
    const float4* p = (const float4*)x + (size_t)i*2;
    float4 v0 = p[0], v1 = p[1];
    uint4 o;
    o.x = pack2(v0.x, v0.y); o.y = pack2(v0.z, v0.w);
    o.z = pack2(v1.x, v1.y); o.w = pack2(v1.z, v1.w);
    ((uint4*)xb)[i] = o;
}

__global__ void count_k(const int* __restrict__ dst, int* __restrict__ counts){
    int e = blockIdx.x*256 + threadIdx.x;
    if (e < EE) atomicAdd(&counts[dst[e]], 1);
}

// ---- hierarchical prefix scan over PADDED counts ((c+3)&~3) ----
__global__ __launch_bounds__(256) void scan1_k(const int* __restrict__ counts,
                                               int* __restrict__ pre, int* __restrict__ bsum){
    int b = blockIdx.x, t = threadIdx.x;
    int base = b*1024 + t*4;
    int4 v = make_int4(0,0,0,0);
    if (base + 3 < NN) v = *(const int4*)(counts + base);
    else {
        int* pv = (int*)&v;
        #pragma unroll
        for (int j=0;j<4;++j) pv[j] = (base+j < NN) ? counts[base+j] : 0;
    }
    v.x = (v.x+3)&~3; v.y = (v.y+3)&~3; v.z = (v.z+3)&~3; v.w = (v.w+3)&~3;
    int s0 = v.x, s1 = s0+v.y, s2 = s1+v.z, s3 = s2+v.w;
    int lane = t & 63, w = t >> 6;
    int incl = s3;
    #pragma unroll
    for (int o=1;o<64;o<<=1){
        int u = __shfl_up(incl, o, 64);
        if (lane >= o) incl += u;
    }
    __shared__ int wsum[4];
    if (lane == 63) wsum[w] = incl;
    __syncthreads();
    int woff = 0;
    #pragma unroll
    for (int i=0;i<4;++i) if (i < w) woff += wsum[i];
    int excl = woff + incl - s3;
    int4 o4 = make_int4(excl, excl+s0, excl+s1, excl+s2);
    if (base + 3 < NN) *(int4*)(pre + base) = o4;
    else {
        int* po = (int*)&o4;
        for (int j=0;j<4;++j) if (base+j < NN) pre[base+j] = po[j];
    }
    if (t == 255) bsum[b] = woff + incl;
}

__global__ __launch_bounds__(256) void scan3_k(const int* __restrict__ pre,
                                               const int* __restrict__ bsum,
                                               int* __restrict__ row_ptr, int* __restrict__ cursor){
    int b = blockIdx.x, t = threadIdx.x;
    __shared__ int boff_s;
    if (t < 64){
        int v = (t < b) ? bsum[t] : 0;
        #pragma unroll
        for (int o=32;o>0;o>>=1) v += __shfl_down(v, o, 64);
        if (t == 0) boff_s = v;
    }
    __syncthreads();
    int boff = boff_s;
    int base = b*1024;
    #pragma unroll
    for (int j=0;j<4;++j){
        int i = base + j*256 + t;
        if (i < NN){
            int r = pre[i] + boff;
            row_ptr[i] = r;
            cursor[i] = r;
        }
    }
    if (b == (int)gridDim.x - 1 && t == 0) row_ptr[NN] = boff + bsum[b];
}

// alive[0..NN-1]=1, alive[NN]=0 (sentinel)
__global__ void init_alive_k(float* __restrict__ a){
    int i = blockIdx.x*256 + threadIdx.x;
    if (i <= NN) a[i] = (i < NN) ? 1.f : 0.f;
}

__global__ void fill_k(const int* __restrict__ src, const int* __restrict__ dst,
                       int* __restrict__ cursor, int* __restrict__ csr_src){
    int e = blockIdx.x*256 + threadIdx.x;
    if (e < EE){
        int p = atomicAdd(&cursor[dst[e]], 1);
        csr_src[p] = src[e];
    }
}

// fill padded tail slots with sentinel NN (after fill_k: cursor[n] = start+count)
__global__ void pad_fill_k(const int* __restrict__ cursor, const int* __restrict__ row_ptr,
                           int* __restrict__ csr_src){
    int n = blockIdx.x*256 + threadIdx.x;
    if (n >= NN) return;
    int e1 = row_ptr[n+1];
    for (int p = cursor[n]; p < e1; ++p) csr_src[p] = NN;
}

__global__ void gstart_k(const int* __restrict__ batch, int* __restrict__ gstart){
    int g = blockIdx.x*256 + threadIdx.x;
    if (g > GG) return;
    if (g == GG){ gstart[GG] = NN; return; }
    int lo = 0, hi = NN;
    while (lo < hi){
        int mid = (lo + hi) >> 1;
        if (batch[mid] < g) lo = mid + 1; else hi = mid;
    }
    gstart[g] = lo;
}

// ---------------- MFMA GEMM, 128-row tiles, LDS B via global_load_lds DMA ----------------
// NP==1: C = elu(A0@B (+bias)).
// NP==4: C = elu( A2@B2 * rowscale + A0@B0 + A1@B1 + A3@B3 ); rowscale applied
//         to the accumulator after the B2 pair (diag-scale commutes).
// FLAGS&1: LN stats. FLAGS&2: bias.
// B staged by async DMA: linear LDS dest (base+lane*16), INVERSE-swizzled global src,
// swizzled ds_read. XOR swizzle is an involution, so read side is unchanged.
template<int FLAGS, int NP>
__global__ __launch_bounds__(256) void mm_k(
    const u16* __restrict__ A0, const u16* __restrict__ A1,
    const u16* __restrict__ A2, const u16* __restrict__ A3,
    const u16* __restrict__ Bb, const float* __restrict__ rowscale,
    const float* __restrict__ bias,
    u16* __restrict__ Cbf, double* __restrict__ stats, int M)
{
    __shared__ u16 Bs[2][128*128];     // 2 x 32 KB
    int tid = threadIdx.x;
    int w = tid >> 6, l = tid & 63;
    int row0 = blockIdx.x * 128;
    int rbase = row0 + w*32 + (l & 15);
    int kq = l >> 4;
    const short8 zz = {0,0,0,0,0,0,0,0};

    f32x4 acc[2][8];
    #pragma unroll
    for (int rt=0;rt<2;++rt)
        #pragma unroll
        for (int ct=0;ct<8;++ct) acc[rt][ct] = (f32x4){0.f,0.f,0.f,0.f};

    // async DMA stage: LDS linear at byte c*16; global src pre-swizzled so that
    // LDS(n,kc) holds B(n, kc^(n&7)) — identical layout to a swizzled ds_write.
    auto stage_dma = [&](const u16* __restrict__ Bp, int buf){
        #pragma unroll
        for (int i=0;i<8;++i){
            int c = i*256 + tid;
            int n = c >> 4, kc = c & 15;
            const u16* src = Bp + n*128 + ((kc ^ (n&7)) << 3);
            u16* dst = (u16*)((char*)&Bs[buf][0] + c*16);
            __builtin_amdgcn_global_load_lds(
                (const __attribute__((address_space(1))) u32*)src,
                (__attribute__((address_space(3))) u32*)dst, 16, 0, 0);
        }
    };

    auto compute = [&](int buf, const u16* __restrict__ Ap){
        #pragma unroll
        for (int ks=0; ks<4; ++ks){
            int kc = ks*4 + kq;
            short8 a[2], b[8];
            #pragma unroll
            for (int rt=0; rt<2; ++rt){
                int gr = rbase + rt*16;
                a[rt] = (gr < M) ? *(const short8*)(Ap + (size_t)gr*128 + kc*8) : zz;
            }
            #pragma unroll
            for (int ct=0; ct<8; ++ct){
                int nf = ct*16 + (l&15);
                b[ct] = *(const short8*)((const char*)&Bs[buf][0] + nf*256 + ((kc ^ (nf&7))<<4));
            }
            #pragma unroll
            for (int rt=0; rt<2; ++rt)
                #pragma unroll
                for (int ct=0; ct<8; ++ct)
                    acc[rt][ct] = __builtin_amdgcn_mfma_f32_16x16x32_bf16(a[rt], b[ct], acc[rt][ct], 0, 0, 0);
        }
    };

    if constexpr (NP == 4){
        stage_dma(Bb + 2*16384, 0);              // B2 first (rowscale ordering)
        __syncthreads();                          // buf0 ready
        stage_dma(Bb, 1);                         // prefetch B0 -> buf1 (in flight under compute)
        compute(0, A2);
        #pragma unroll
        for (int rt=0; rt<2; ++rt){
            #pragma unroll
            for (int i=0; i<4; ++i){
                int row = row0 + w*32 + rt*16 + (l>>4)*4 + i;
                float d = (row < M) ? rowscale[row] : 0.f;
                #pragma unroll
                for (int ct=0; ct<8; ++ct) acc[rt][ct][i] *= d;
            }
        }
        __syncthreads();                          // drain B0 DMA; buf0 reads done
        stage_dma(Bb + 16384, 0);                 // prefetch B1 -> buf0
        compute(1, A0);
        __syncthreads();
        stage_dma(Bb + 3*16384, 1);               // prefetch B3 -> buf1
        compute(0, A1);
        __syncthreads();
        compute(1, A3);
    } else {
        stage_dma(Bb, 0);
        __syncthreads();
        compute(0, A0);
    }

    float ls = 0.f, lq = 0.f;
    float bcol[8];
    if constexpr (FLAGS & 2){
        #pragma unroll
        for (int ct=0; ct<8; ++ct) bcol[ct] = bias[ct*16 + (l&15)];
    }
    #pragma unroll
    for (int rt=0; rt<2; ++rt){
        #pragma unroll
        for (int i=0; i<4; ++i){
            int row = row0 + w*32 + rt*16 + (l>>4)*4 + i;
            if (row >= M) continue;
            #pragma unroll
            for (int ct=0; ct<8; ++ct){
                float v = acc[rt][ct][i];
                if constexpr (FLAGS & 2) v += bcol[ct];
                v = elu_f(v);
                Cbf[(size_t)row*128 + ct*16 + (l&15)] = f2bf(v);
                if constexpr (FLAGS & 1){ ls += v; lq = fmaf(v, v, lq); }
            }
        }
    }
    if constexpr (FLAGS & 1){
        double s = ls, q = lq;
        #pragma unroll
        for (int o=32;o>0;o>>=1){ s += __shfl_xor(s,o,64); q += __shfl_xor(q,o,64); }
        __shared__ double sw[4], qw[4];
        if (l == 0){ sw[w] = s; qw[w] = q; }
        __syncthreads();
        if (tid == 0){
            atomicAdd(&stats[0], sw[0]+sw[1]+sw[2]+sw[3]);
            atomicAdd(&stats[1], qw[0]+qw[1]+qw[2]+qw[3]);
        }
    }
}

// ---------------- per-layer graph kernels ----------------

// wave per node: deg = 1 + sum alive[nbr] (alive n), else 1e-6.
// ar2[n] = (alive, alive*rsqrt(deg)); invdeg[n] = 1/deg; also refresh ar2[NN]=(0,0)
__global__ __launch_bounds__(256) void deg2_k(const int* __restrict__ rp, const int* __restrict__ cs,
                                              const float* __restrict__ alive,
                                              float2* __restrict__ ar2, float* __restrict__ invdeg){
    if (blockIdx.x == 0 && threadIdx.x == 0) ar2[NN] = make_float2(0.f, 0.f);
    int n = (blockIdx.x*256 + threadIdx.x) >> 6;
    int lane = threadIdx.x & 63;
    if (n >= NN) return;
    int e0 = rp[n], e1 = rp[n+1];
    float c = 0.f;
    for (int e = e0 + lane; e < e1; e += 64) c += alive[cs[e]];
    #pragma unroll
    for (int o=32;o>0;o>>=1) c += __shfl_xor(c, o, 64);
    if (lane == 0){
        float al = alive[n];
        float d = (al == 0.f) ? 1e-6f : fmaxf(1.f + c, 1e-6f);
        ar2[n] = make_float2(al, al * rsqrtf(d));
        invdeg[n] = 1.f / d;
    }
}

// ONE WAVE PER BLOCK, padded branch-free unroll-4 gather:
// sagg = sum w.x*h[s] + h[n];  gagg = rn*(sum w.y*h[s] + rn*h[n])
__global__ __launch_bounds__(64) void agg_k(const u16* __restrict__ h,
    const int* __restrict__ rp, const int* __restrict__ cs,
    const float2* __restrict__ ar2,
    u16* __restrict__ sagg, u16* __restrict__ gagg){
    int n = blockIdx.x;
    int lane = threadIdx.x;
    float2 an = ar2[n];
    u32* so = (u32*)(sagg + (size_t)n*HH);
    u32* go = (u32*)(gagg + (size_t)n*HH);
    if (an.x == 0.f){ so[lane]=0u; go[lane]=0u; return; }
    float rn = an.y;
    int e0 = rp[n], e1 = rp[n+1];
    float sx=0.f, sy=0.f, gx=0.f, gy=0.f;
    for (int e = e0; e < e1; e += 4){
        int i0 = cs[e], i1 = cs[e+1], i2 = cs[e+2], i3 = cs[e+3];
        float2 w0 = ar2[i0], w1 = ar2[i1], w2 = ar2[i2], w3 = ar2[i3];
        u32 h0 = *(const u32*)(h + (size_t)i0*HH + lane*2);
        u32 h1 = *(const u32*)(h + (size_t)i1*HH + lane*2);
        u32 h2 = *(const u32*)(h + (size_t)i2*HH + lane*2);
        u32 h3 = *(const u32*)(h + (size_t)i3*HH + lane*2);
        float ax, ay;
        ax = bf2f((u16)(h0 & 0xffffu)); ay = bf2f((u16)(h0 >> 16));
        sx = fmaf(w0.x, ax, sx); sy = fmaf(w0.x, ay, sy);
        gx = fmaf(w0.y, ax, gx); gy = fmaf(w0.y, ay, gy);
        ax = bf2f((u16)(h1 & 0xffffu)); ay = bf2f((u16)(h1 >> 16));
        sx = fmaf(w1.x, ax, sx); sy = fmaf(w1.x, ay, sy);
        gx = fmaf(w1.y, ax, gx); gy = fmaf(w1.y, ay, gy);
        ax = bf2f((u16)(h2 & 0xffffu)); ay = bf2f((u16)(h2 >> 16));
        sx = fmaf(w2.x, ax, sx); sy = fmaf(w2.x, ay, sy);
        gx = fmaf(w2.y, ax, gx); gy = fmaf(w2.y, ay, gy);
        ax = bf2f((u16)(h3 & 0xffffu)); ay = bf2f((u16)(h3 >> 16));
        sx = fmaf(w3.x, ax, sx); sy = fmaf(w3.x, ay, sy);
        gx = fmaf(w3.y, ax, gx); gy = fmaf(w3.y, ay, gy);
    }
    u32 hn = *(const u32*)(h + (size_t)n*HH + lane*2);
    float hx = bf2f((u16)(hn & 0xffffu)), hy = bf2f((u16)(hn >> 16));
    sx += hx; sy += hy;
    gx = fmaf(rn, hx, gx); gy = fmaf(rn, hy, gy);
    so[lane] = pack2(sx, sy);
    go[lane] = pack2(rn*gx, rn*gy);
}

// ---------------- fused LayerNorm + gate pooling + readout, one block per graph ----------------
__global__ __launch_bounds__(1024) void lnro_k(u16* __restrict__ hb,
                                               const double* __restrict__ stats,
                                               const float* __restrict__ p0,
                                               const float* __restrict__ p1,
                                               const float* __restrict__ pa,
                                               const float* __restrict__ row,
                                               const int* __restrict__ gstart,
                                               float* __restrict__ alive,
                                               float* __restrict__ rep){
    int g = blockIdx.x, tid = threadIdx.x;
    int w = tid >> 6, lane = tid & 63;
    int beg = gstart[g], end = gstart[g+1];
    const double tot = (double)NN * (double)HH;
    double m = stats[0] / tot;
    double var = stats[1] / tot - m*m;
    float mf = (float)m;
    float rs = rsqrtf((float)var + 1e-5f);
    float2 q0 = ((const float2*)p0)[lane];
    float2 q1 = ((const float2*)p1)[lane];
    float pa0 = pa[0], pa1 = pa[1], pa2 = pa[2];
    float csx = 0.f, csy = 0.f, cmx = -INFINITY, cmy = -INFINITY;
    for (int n = beg + w; n < end; n += 16){
        u32 hv = ((u32*)(hb + (size_t)n*HH))[lane];
        float vx = (bf2f((u16)(hv & 0xffffu)) - mf) * rs;
        float vy = (bf2f((u16)(hv >> 16))    - mf) * rs;
        float d0 = vx*q0.x + vy*q0.y;
        float d1 = vx*q1.x + vy*q1.y;
        #pragma unroll
        for (int o=32;o>0;o>>=1){ d0 += __shfl_xor(d0,o,64); d1 += __shfl_xor(d1,o,64); }
        float g1 = 1.f/(1.f + expf(-d0));
        float g2 = tanhf(d1);
        float gate = pa0*g1 + pa1*g2 + pa2;
        float keep = gate > THR ? 1.f : 0.f;
        float sc = gate*keep;
        vx *= sc; vy *= sc;
        ((u32*)(hb + (size_t)n*HH))[lane] = pack2(vx, vy);
        if (lane == 0 && keep == 0.f) alive[n] = 0.f;
        csx += vx; csy += vy;
        cmx = fmaxf(cmx, vx); cmy = fmaxf(cmy, vy);
    }
    __shared__ float ls[16][HH];
    __shared__ float lm[16][HH];
    ls[w][2*lane] = csx; ls[w][2*lane+1] = csy;
    lm[w][2*lane] = cmx; lm[w][2*lane+1] = cmy;
    __syncthreads();
    if (tid < HH){
        float s = 0.f, mx = -INFINITY;
        #pragma unroll
        for (int i=0;i<16;++i){ s += ls[i][tid]; mx = fmaxf(mx, lm[i][tid]); }
        if (mx == -INFINITY) mx = 0.f;
        float cnt = (float)(end - beg);
        float mean = s / fmaxf(cnt, 1.f);
        rep[(size_t)g*HH + tid] = row[0]*mean + row[1]*mx + row[2]*s;
    }
}

// standalone mixed readout (initial layer), 1024 threads = 8 row-stripes
__global__ __launch_bounds__(1024) void readout_k(const u16* __restrict__ h,
                                                  const int* __restrict__ gstart,
                                                  const float* __restrict__ w,
                                                  float* __restrict__ rep){
    int g = blockIdx.x;
    int t = threadIdx.x & 127, q = threadIdx.x >> 7;   // q in 0..7
    int beg = gstart[g], end = gstart[g+1];
    float sum = 0.f, mx = -INFINITY;
    for (int n = beg + q; n < end; n += 8){
        float v = bf2f(h[(size_t)n*HH + t]);
        sum += v;
        mx = fmaxf(mx, v);
    }
    __shared__ float ss[8][HH];
    __shared__ float ms[8][HH];
    ss[q][t] = sum; ms[q][t] = mx;
    __syncthreads();
    if (threadIdx.x < HH){
        float s = 0.f, m = -INFINITY;
        #pragma unroll
        for (int i=0;i<8;++i){ s += ss[i][threadIdx.x]; m = fmaxf(m, ms[i][threadIdx.x]); }
        if (m == -INFINITY) m = 0.f;
        float cnt = (float)(end - beg);
        float mean = s / fmaxf(cnt, 1.f);
        rep[(size_t)g*HH + threadIdx.x] = w[0]*mean + w[1]*m + w[2]*s;
    }
}

__global__ __launch_bounds__(128) void final_k(const float* __restrict__ reps,
                                               const float* __restrict__ la,
                                               const float* __restrict__ loW,
                                               const float* __restrict__ lob,
                                               const float* __restrict__ cW,
                                               const float* __restrict__ cb,
                                               float* __restrict__ out){
    int g = blockIdx.x, t = threadIdx.x;
    float r0 = reps[(size_t)(0*GG+g)*HH + t];
    float r1 = reps[(size_t)(1*GG+g)*HH + t];
    float r2 = reps[(size_t)(2*GG+g)*HH + t];
    float r3 = reps[(size_t)(3*GG+g)*HH + t];
    float s = r0+r1+r2+r3;
    float mean = 0.25f*s;
    float mx = fmaxf(fmaxf(r0,r1), fmaxf(r2,r3));
    float z = la[0]*elu_f(s) + la[1]*elu_f(mean) + la[2]*elu_f(mx);
    __shared__ float zs[HH];
    zs[t] = z;
    __syncthreads();
    float a = lob[t];
    for (int k=0;k<HH;++k) a = fmaf(zs[k], loW[(size_t)k*HH + t], a);
    float z2 = elu_f(a);
    __shared__ float z2s[HH];
    z2s[t] = z2;
    __syncthreads();
    __shared__ float lg[OUTC];
    if (t < OUTC){
        float acc = cb[t];
        for (int k=0;k<HH;++k) acc = fmaf(z2s[k], cW[(size_t)k*OUTC + t], acc);
        lg[t] = acc;
    }
    __syncthreads();
    if (t == 0){
        float m = lg[0];
        for (int o=1;o<OUTC;++o) m = fmaxf(m, lg[o]);
        float se = 0.f;
        for (int o=0;o<OUTC;++o) se += expf(lg[o]-m);
        float lse = m + logf(se);
        for (int o=0;o<OUTC;++o) out[(size_t)g*OUTC + o] = lg[o] - lse;
    }
}

// ---------------- host launch ----------------

extern "C" void kernel_launch(void* const* d_in, const int* in_sizes, int n_in,
                              void* d_out, int out_size, void* d_ws, size_t ws_size,
                              hipStream_t stream){
    const float* x     = (const float*)d_in[0];
    const int*   ei    = (const int*)d_in[1];
    const int*   batch = (const int*)d_in[2];
    const float* l1W   = (const float*)d_in[3];
    const float* l1b   = (const float*)d_in[4];
    const float* gW    = (const float*)d_in[5];
    const float* poolp = (const float*)d_in[6];
    const float* loW   = (const float*)d_in[7];
    const float* lob   = (const float*)d_in[8];
    const float* cW    = (const float*)d_in[9];
    const float* cb    = (const float*)d_in[10];
    const float* nalog = (const float*)d_in[11];
    const float* pllog = (const float*)d_in[12];
    const float* rolog = (const float*)d_in[13];
    const float* lalog = (const float*)d_in[14];
    float* out = (float*)d_out;

    char* wsb = (char*)d_ws;
    size_t off = 0;
    auto alloc = [&](size_t bytes)->char* {
        char* p = wsb + off;
        off += (bytes + 255) & ~(size_t)255;
        return p;
    };
    const int EEP = EE + 3*NN + 16;                 // padded CSR capacity
    u16*   hb     = (u16*)alloc(sizeof(u16)*(size_t)(NN+1)*HH);  // +1 sentinel row
    u16*   xb     = (u16*)alloc(sizeof(u16)*(size_t)NN*HH);
    u16*   sagg   = (u16*)alloc(sizeof(u16)*(size_t)NN*HH);
    u16*   gagg   = (u16*)alloc(sizeof(u16)*(size_t)NN*HH);
    u16*   Wc     = (u16*)alloc(sizeof(u16)*(size_t)LL*4*HH*HH);
    u16*   lin1t  = (u16*)alloc(sizeof(u16)*HH*HH);
    int*   row_ptr= (int*)alloc(sizeof(int)*(NN+1));
    int*   counts = (int*)alloc(sizeof(int)*NN);
    int*   cursor = (int*)alloc(sizeof(int)*NN);
    int*   pre    = (int*)alloc(sizeof(int)*NN);
    int*   bsum   = (int*)alloc(sizeof(int)*64);
    int*   csr_src= (int*)alloc(sizeof(int)*EEP);
    float2* ar2   = (float2*)alloc(sizeof(float2)*(NN+1));       // +1 sentinel
    float* invdeg = (float*)alloc(sizeof(float)*NN);
    float* alive  = (float*)alloc(sizeof(float)*(NN+1));         // +1 sentinel
    int*   gstart = (int*)alloc(sizeof(int)*(GG+1));
    float* reps   = (float*)alloc(sizeof(float)*(size_t)(LL+1)*GG*HH);
    float* coef   = (float*)alloc(sizeof(float)*64);
    double* stats = (double*)alloc(sizeof(double)*2*LL);

    const int* srcp = ei;
    const int* dstp = ei + EE;

    hipMemsetAsync(counts, 0, sizeof(int)*NN, stream);
    hipMemsetAsync(stats, 0, sizeof(double)*2*LL, stream);

    const int SCAN_BLOCKS = (NN + 1023)/1024;   // 49

    prep_coef_k<<<1, 64, 0, stream>>>(nalog, pllog, rolog, lalog, coef);
    prep_w_k<<<(LL*4*16384 + 16384 + 255)/256, 256, 0, stream>>>(gW, l1W, coef, Wc, lin1t);
    count_k<<<(EE + 255)/256, 256, 0, stream>>>(dstp, counts);
    scan1_k<<<SCAN_BLOCKS, 256, 0, stream>>>(counts, pre, bsum);
    scan3_k<<<SCAN_BLOCKS, 256, 0, stream>>>(pre, bsum, row_ptr, cursor);
    fill_k<<<(EE + 255)/256, 256, 0, stream>>>(srcp, dstp, cursor, csr_src);
    pad_fill_k<<<(NN + 255)/256, 256, 0, stream>>>(cursor, row_ptr, csr_src);
    gstart_k<<<(GG + 256)/256, 256, 0, stream>>>(batch, gstart);
    init_alive_k<<<(NN + 256)/256, 256, 0, stream>>>(alive);
    x2bf_k<<<(NN*HH/8 + 255)/256, 256, 0, stream>>>(x, xb);

    const int gemm_blocks = (NN + 127)/128;   // 128-row tiles -> 391 blocks

    // h = elu(x @ lin1_W + b) -> bf16
    mm_k<2,1><<<gemm_blocks, 256, 0, stream>>>(xb, nullptr, nullptr, nullptr,
                                               lin1t, nullptr, l1b, hb, nullptr, NN);
    readout_k<<<GG, 1024, 0, stream>>>(hb, gstart, coef + 21, reps);

    for (int i=0;i<LL;++i){
        deg2_k<<<(NN + 3)/4, 256, 0, stream>>>(row_ptr, csr_src, alive, ar2, invdeg);
        agg_k<<<NN, 64, 0, stream>>>(hb, row_ptr, csr_src, ar2, sagg, gagg);
        mm_k<1,4><<<gemm_blocks, 256, 0, stream>>>(hb, sagg, sagg, gagg,
                                                   Wc + (size_t)i*4*16384, invdeg, nullptr,
                                                   hb, stats + 2*i, NN);
        lnro_k<<<GG, 1024, 0, stream>>>(hb, stats + 2*i,
                                        poolp + (size_t)(i*2+0)*HH,
                                        poolp + (size_t)(i*2+1)*HH,
                                        coef + 12 + i*3,
                                        coef + 21 + (i+1)*3,
                                        gstart, alive,
                                        reps + (size_t)(i+1)*GG*HH);
    }

    final_k<<<GG, HH, 0, stream>>>(reps, coef + 33, loW, lob, cW, cb, out);
}

// Round 12
// 504.165 us; speedup vs baseline: 1.0585x; 1.0585x over previous
//
#include <hip/hip_runtime.h>
#include <math.h>

#define NN 50000
#define EE 800000
#define GG 512
#define HH 128
#define LL 3
#define OUTC 10
#define THR 0.01f

typedef unsigned short u16;
typedef unsigned int u32;
typedef __attribute__((ext_vector_type(8))) short short8;
typedef __attribute__((ext_vector_type(4))) float f32x4;

__device__ __forceinline__ float elu_f(float x){ return x > 0.f ? x : (expf(x)-1.f); }
__device__ __forceinline__ u16 f2bf(float f){
    u32 u = __float_as_uint(f);
    return (u16)((u + 0x7fffu + ((u>>16)&1u)) >> 16);
}
__device__ __forceinline__ float bf2f(u16 b){ return __uint_as_float(((u32)b)<<16); }
__device__ __forceinline__ u32 pack2(float a, float b){
    return (u32)f2bf(a) | ((u32)f2bf(b)<<16);
}

// ---------------- setup kernels ----------------

__device__ void softmax_row(const float* in, float* out, int c){
    float m = in[0];
    for (int j=1;j<c;++j) m = fmaxf(m, in[j]);
    float s = 0.f;
    for (int j=0;j<c;++j){ float e = expf(in[j]-m); out[j]=e; s+=e; }
    for (int j=0;j<c;++j) out[j] /= s;
}

// coef layout: na[12] @0, pool[9] @12, ro[12] @21, la[3] @33
__global__ void prep_coef_k(const float* __restrict__ na, const float* __restrict__ pl,
                            const float* __restrict__ ro, const float* __restrict__ la,
                            float* __restrict__ coef){
    if (threadIdx.x != 0 || blockIdx.x != 0) return;
    for (int i=0;i<LL;++i)   softmax_row(na + i*4, coef + i*4, 4);
    for (int i=0;i<LL;++i)   softmax_row(pl + i*3, coef + 12 + i*3, 3);
    for (int i=0;i<LL+1;++i) softmax_row(ro + i*3, coef + 21 + i*3, 3);
    softmax_row(la, coef + 33, 3);
}

// Per-layer combined B stacks, bf16, TRANSPOSED to [n][k]:
// B0 = a1*W2+a2*W3+a3*W4 (h), B1 = a2*W3+a3*W5 (sagg), B2 = a1*W1 (sagg*invdeg), B3 = a0*W0 (gagg)
__global__ __launch_bounds__(256) void prep_w_k(const float* __restrict__ gW,
                                                const float* __restrict__ lin1W,
                                                const float* __restrict__ coef,
                                                u16* __restrict__ Wc, u16* __restrict__ lin1t){
    int idx = blockIdx.x*256 + threadIdx.x;
    const int total = LL*4*16384;
    if (idx < total){
        int i = idx >> 16;
        int rem = idx & 65535;
        int p = rem >> 14;
        int j = rem & 16383;
        int n = j >> 7, k = j & 127;
        const float* W = gW + (size_t)i*6*16384;
        float a0=coef[i*4], a1=coef[i*4+1], a2=coef[i*4+2], a3=coef[i*4+3];
        int e = k*128 + n;
        float v;
        if (p==0)      v = a1*W[2*16384+e] + a2*W[3*16384+e] + a3*W[4*16384+e];
        else if (p==1) v = a2*W[3*16384+e] + a3*W[5*16384+e];
        else if (p==2) v = a1*W[1*16384+e];
        else           v = a0*W[0*16384+e];
        Wc[(size_t)(i*4+p)*16384 + n*128 + k] = f2bf(v);
    } else if (idx < total + 16384){
        int j = idx - total;
        int n = j >> 7, k = j & 127;
        lin1t[n*128 + k] = f2bf(lin1W[k*128 + n]);
    }
}

__global__ void x2bf_k(const float* __restrict__ x, u16* __restrict__ xb){
    int i = blockIdx.x*256 + threadIdx.x;
    if (i >= NN*HH/8) return;
    const float4* p = (const float4*)x + (size_t)i*2;
    float4 v0 = p[0], v1 = p[1];
    uint4 o;
    o.x = pack2(v0.x, v0.y); o.y = pack2(v0.z, v0.w);
    o.z = pack2(v1.x, v1.y); o.w = pack2(v1.z, v1.w);
    ((uint4*)xb)[i] = o;
}

__global__ void count_k(const int* __restrict__ dst, int* __restrict__ counts){
    int e = blockIdx.x*256 + threadIdx.x;
    if (e < EE) atomicAdd(&counts[dst[e]], 1);
}

// ---- hierarchical prefix scan over PADDED counts ((c+3)&~3) ----
__global__ __launch_bounds__(256) void scan1_k(const int* __restrict__ counts,
                                               int* __restrict__ pre, int* __restrict__ bsum){
    int b = blockIdx.x, t = threadIdx.x;
    int base = b*1024 + t*4;
    int4 v = make_int4(0,0,0,0);
    if (base + 3 < NN) v = *(const int4*)(counts + base);
    else {
        int* pv = (int*)&v;
        #pragma unroll
        for (int j=0;j<4;++j) pv[j] = (base+j < NN) ? counts[base+j] : 0;
    }
    v.x = (v.x+3)&~3; v.y = (v.y+3)&~3; v.z = (v.z+3)&~3; v.w = (v.w+3)&~3;
    int s0 = v.x, s1 = s0+v.y, s2 = s1+v.z, s3 = s2+v.w;
    int lane = t & 63, w = t >> 6;
    int incl = s3;
    #pragma unroll
    for (int o=1;o<64;o<<=1){
        int u = __shfl_up(incl, o, 64);
        if (lane >= o) incl += u;
    }
    __shared__ int wsum[4];
    if (lane == 63) wsum[w] = incl;
    __syncthreads();
    int woff = 0;
    #pragma unroll
    for (int i=0;i<4;++i) if (i < w) woff += wsum[i];
    int excl = woff + incl - s3;
    int4 o4 = make_int4(excl, excl+s0, excl+s1, excl+s2);
    if (base + 3 < NN) *(int4*)(pre + base) = o4;
    else {
        int* po = (int*)&o4;
        for (int j=0;j<4;++j) if (base+j < NN) pre[base+j] = po[j];
    }
    if (t == 255) bsum[b] = woff + incl;
}

__global__ __launch_bounds__(256) void scan3_k(const int* __restrict__ pre,
                                               const int* __restrict__ bsum,
                                               int* __restrict__ row_ptr, int* __restrict__ cursor){
    int b = blockIdx.x, t = threadIdx.x;
    __shared__ int boff_s;
    if (t < 64){
        int v = (t < b) ? bsum[t] : 0;
        #pragma unroll
        for (int o=32;o>0;o>>=1) v += __shfl_down(v, o, 64);
        if (t == 0) boff_s = v;
    }
    __syncthreads();
    int boff = boff_s;
    int base = b*1024;
    #pragma unroll
    for (int j=0;j<4;++j){
        int i = base + j*256 + t;
        if (i < NN){
            int r = pre[i] + boff;
            row_ptr[i] = r;
            cursor[i] = r;
        }
    }
    if (b == (int)gridDim.x - 1 && t == 0) row_ptr[NN] = boff + bsum[b];
}

// alive[0..NN-1]=1, alive[NN]=0 (sentinel)
__global__ void init_alive_k(float* __restrict__ a){
    int i = blockIdx.x*256 + threadIdx.x;
    if (i <= NN) a[i] = (i < NN) ? 1.f : 0.f;
}

__global__ void fill_k(const int* __restrict__ src, const int* __restrict__ dst,
                       int* __restrict__ cursor, int* __restrict__ csr_src){
    int e = blockIdx.x*256 + threadIdx.x;
    if (e < EE){
        int p = atomicAdd(&cursor[dst[e]], 1);
        csr_src[p] = src[e];
    }
}

// fill padded tail slots with sentinel NN (after fill_k: cursor[n] = start+count)
__global__ void pad_fill_k(const int* __restrict__ cursor, const int* __restrict__ row_ptr,
                           int* __restrict__ csr_src){
    int n = blockIdx.x*256 + threadIdx.x;
    if (n >= NN) return;
    int e1 = row_ptr[n+1];
    for (int p = cursor[n]; p < e1; ++p) csr_src[p] = NN;
}

__global__ void gstart_k(const int* __restrict__ batch, int* __restrict__ gstart){
    int g = blockIdx.x*256 + threadIdx.x;
    if (g > GG) return;
    if (g == GG){ gstart[GG] = NN; return; }
    int lo = 0, hi = NN;
    while (lo < hi){
        int mid = (lo + hi) >> 1;
        if (batch[mid] < g) lo = mid + 1; else hi = mid;
    }
    gstart[g] = lo;
}

// ---------------- MFMA GEMM, 128-row tiles, 512 threads (8 waves), LDS B via DMA ----------------
// Wave w owns a 32-row x 64-col quadrant: rows (w>>1)*32, cols (w&1)*64. acc = 2x4 frags.
// NP==1: C = elu(A0@B (+bias)).
// NP==4: C = elu( A2@B2 * rowscale + A0@B0 + A1@B1 + A3@B3 ).
// FLAGS&1: LN stats. FLAGS&2: bias.
template<int FLAGS, int NP>
__global__ __launch_bounds__(512) void mm_k(
    const u16* __restrict__ A0, const u16* __restrict__ A1,
    const u16* __restrict__ A2, const u16* __restrict__ A3,
    const u16* __restrict__ Bb, const float* __restrict__ rowscale,
    const float* __restrict__ bias,
    u16* __restrict__ Cbf, double* __restrict__ stats, int M)
{
    __shared__ u16 Bs[2][128*128];     // 2 x 32 KB
    int tid = threadIdx.x;
    int w = tid >> 6, l = tid & 63;
    int rq = w >> 1;                   // row quadrant 0..3 (32 rows each)
    int ch = w & 1;                    // col half 0..1 (64 cols each)
    int row0 = blockIdx.x * 128;
    int rbase = row0 + rq*32 + (l & 15);
    int kq = l >> 4;
    const short8 zz = {0,0,0,0,0,0,0,0};

    f32x4 acc[2][4];
    #pragma unroll
    for (int rt=0;rt<2;++rt)
        #pragma unroll
        for (int ct=0;ct<4;++ct) acc[rt][ct] = (f32x4){0.f,0.f,0.f,0.f};

    // async DMA stage: LDS linear at byte c*16; global src pre-swizzled so that
    // LDS(n,kc) holds B(n, kc^(n&7)) — same layout as a swizzled ds_write.
    auto stage_dma = [&](const u16* __restrict__ Bp, int buf){
        #pragma unroll
        for (int i=0;i<4;++i){
            int c = i*512 + tid;
            int n = c >> 4, kc = c & 15;
            const u16* src = Bp + n*128 + ((kc ^ (n&7)) << 3);
            u16* dst = (u16*)((char*)&Bs[buf][0] + c*16);
            __builtin_amdgcn_global_load_lds(
                (const __attribute__((address_space(1))) u32*)src,
                (__attribute__((address_space(3))) u32*)dst, 16, 0, 0);
        }
    };

    auto compute = [&](int buf, const u16* __restrict__ Ap){
        #pragma unroll
        for (int ks=0; ks<4; ++ks){
            int kc = ks*4 + kq;
            short8 a[2], b[4];
            #pragma unroll
            for (int rt=0; rt<2; ++rt){
                int gr = rbase + rt*16;
                a[rt] = (gr < M) ? *(const short8*)(Ap + (size_t)gr*128 + kc*8) : zz;
            }
            #pragma unroll
            for (int ct=0; ct<4; ++ct){
                int nf = ch*64 + ct*16 + (l&15);
                b[ct] = *(const short8*)((const char*)&Bs[buf][0] + nf*256 + ((kc ^ (nf&7))<<4));
            }
            #pragma unroll
            for (int rt=0; rt<2; ++rt)
                #pragma unroll
                for (int ct=0; ct<4; ++ct)
                    acc[rt][ct] = __builtin_amdgcn_mfma_f32_16x16x32_bf16(a[rt], b[ct], acc[rt][ct], 0, 0, 0);
        }
    };

    if constexpr (NP == 4){
        stage_dma(Bb + 2*16384, 0);              // B2 first (rowscale ordering)
        __syncthreads();                          // buf0 ready
        stage_dma(Bb, 1);                         // prefetch B0 -> buf1
        compute(0, A2);
        #pragma unroll
        for (int rt=0; rt<2; ++rt){
            #pragma unroll
            for (int i=0; i<4; ++i){
                int row = row0 + rq*32 + rt*16 + (l>>4)*4 + i;
                float d = (row < M) ? rowscale[row] : 0.f;
                #pragma unroll
                for (int ct=0; ct<4; ++ct) acc[rt][ct][i] *= d;
            }
        }
        __syncthreads();                          // drain B0 DMA
        stage_dma(Bb + 16384, 0);                 // prefetch B1 -> buf0
        compute(1, A0);
        __syncthreads();
        stage_dma(Bb + 3*16384, 1);               // prefetch B3 -> buf1
        compute(0, A1);
        __syncthreads();
        compute(1, A3);
    } else {
        stage_dma(Bb, 0);
        __syncthreads();
        compute(0, A0);
    }

    float ls = 0.f, lq = 0.f;
    float bcol[4];
    if constexpr (FLAGS & 2){
        #pragma unroll
        for (int ct=0; ct<4; ++ct) bcol[ct] = bias[ch*64 + ct*16 + (l&15)];
    }
    #pragma unroll
    for (int rt=0; rt<2; ++rt){
        #pragma unroll
        for (int i=0; i<4; ++i){
            int row = row0 + rq*32 + rt*16 + (l>>4)*4 + i;
            if (row >= M) continue;
            #pragma unroll
            for (int ct=0; ct<4; ++ct){
                float v = acc[rt][ct][i];
                if constexpr (FLAGS & 2) v += bcol[ct];
                v = elu_f(v);
                Cbf[(size_t)row*128 + ch*64 + ct*16 + (l&15)] = f2bf(v);
                if constexpr (FLAGS & 1){ ls += v; lq = fmaf(v, v, lq); }
            }
        }
    }
    if constexpr (FLAGS & 1){
        double s = ls, q = lq;
        #pragma unroll
        for (int o=32;o>0;o>>=1){ s += __shfl_xor(s,o,64); q += __shfl_xor(q,o,64); }
        __shared__ double sw[8], qw[8];
        if (l == 0){ sw[w] = s; qw[w] = q; }
        __syncthreads();
        if (tid == 0){
            double S = 0.0, Q = 0.0;
            #pragma unroll
            for (int i=0;i<8;++i){ S += sw[i]; Q += qw[i]; }
            atomicAdd(&stats[0], S);
            atomicAdd(&stats[1], Q);
        }
    }
}

// ---------------- per-layer graph kernels ----------------

// wave per node: deg = 1 + sum alive[nbr] (alive n), else 1e-6.
// ar2[n] = (alive, alive*rsqrt(deg)); invdeg[n] = 1/deg; also refresh ar2[NN]=(0,0)
__global__ __launch_bounds__(256) void deg2_k(const int* __restrict__ rp, const int* __restrict__ cs,
                                              const float* __restrict__ alive,
                                              float2* __restrict__ ar2, float* __restrict__ invdeg){
    if (blockIdx.x == 0 && threadIdx.x == 0) ar2[NN] = make_float2(0.f, 0.f);
    int n = (blockIdx.x*256 + threadIdx.x) >> 6;
    int lane = threadIdx.x & 63;
    if (n >= NN) return;
    int e0 = rp[n], e1 = rp[n+1];
    float c = 0.f;
    for (int e = e0 + lane; e < e1; e += 64) c += alive[cs[e]];
    #pragma unroll
    for (int o=32;o>0;o>>=1) c += __shfl_xor(c, o, 64);
    if (lane == 0){
        float al = alive[n];
        float d = (al == 0.f) ? 1e-6f : fmaxf(1.f + c, 1e-6f);
        ar2[n] = make_float2(al, al * rsqrtf(d));
        invdeg[n] = 1.f / d;
    }
}

// ONE WAVE PER BLOCK, padded branch-free unroll-4 gather:
// sagg = sum w.x*h[s] + h[n];  gagg = rn*(sum w.y*h[s] + rn*h[n])
__global__ __launch_bounds__(64) void agg_k(const u16* __restrict__ h,
    const int* __restrict__ rp, const int* __restrict__ cs,
    const float2* __restrict__ ar2,
    u16* __restrict__ sagg, u16* __restrict__ gagg){
    int n = blockIdx.x;
    int lane = threadIdx.x;
    float2 an = ar2[n];
    u32* so = (u32*)(sagg + (size_t)n*HH);
    u32* go = (u32*)(gagg + (size_t)n*HH);
    if (an.x == 0.f){ so[lane]=0u; go[lane]=0u; return; }
    float rn = an.y;
    int e0 = rp[n], e1 = rp[n+1];
    float sx=0.f, sy=0.f, gx=0.f, gy=0.f;
    for (int e = e0; e < e1; e += 4){
        int i0 = cs[e], i1 = cs[e+1], i2 = cs[e+2], i3 = cs[e+3];
        float2 w0 = ar2[i0], w1 = ar2[i1], w2 = ar2[i2], w3 = ar2[i3];
        u32 h0 = *(const u32*)(h + (size_t)i0*HH + lane*2);
        u32 h1 = *(const u32*)(h + (size_t)i1*HH + lane*2);
        u32 h2 = *(const u32*)(h + (size_t)i2*HH + lane*2);
        u32 h3 = *(const u32*)(h + (size_t)i3*HH + lane*2);
        float ax, ay;
        ax = bf2f((u16)(h0 & 0xffffu)); ay = bf2f((u16)(h0 >> 16));
        sx = fmaf(w0.x, ax, sx); sy = fmaf(w0.x, ay, sy);
        gx = fmaf(w0.y, ax, gx); gy = fmaf(w0.y, ay, gy);
        ax = bf2f((u16)(h1 & 0xffffu)); ay = bf2f((u16)(h1 >> 16));
        sx = fmaf(w1.x, ax, sx); sy = fmaf(w1.x, ay, sy);
        gx = fmaf(w1.y, ax, gx); gy = fmaf(w1.y, ay, gy);
        ax = bf2f((u16)(h2 & 0xffffu)); ay = bf2f((u16)(h2 >> 16));
        sx = fmaf(w2.x, ax, sx); sy = fmaf(w2.x, ay, sy);
        gx = fmaf(w2.y, ax, gx); gy = fmaf(w2.y, ay, gy);
        ax = bf2f((u16)(h3 & 0xffffu)); ay = bf2f((u16)(h3 >> 16));
        sx = fmaf(w3.x, ax, sx); sy = fmaf(w3.x, ay, sy);
        gx = fmaf(w3.y, ax, gx); gy = fmaf(w3.y, ay, gy);
    }
    u32 hn = *(const u32*)(h + (size_t)n*HH + lane*2);
    float hx = bf2f((u16)(hn & 0xffffu)), hy = bf2f((u16)(hn >> 16));
    sx += hx; sy += hy;
    gx = fmaf(rn, hx, gx); gy = fmaf(rn, hy, gy);
    so[lane] = pack2(sx, sy);
    go[lane] = pack2(rn*gx, rn*gy);
}

// ---------------- fused LayerNorm + gate pooling + readout, one block per graph ----------------
__global__ __launch_bounds__(1024) void lnro_k(u16* __restrict__ hb,
                                               const double* __restrict__ stats,
                                               const float* __restrict__ p0,
                                               const float* __restrict__ p1,
                                               const float* __restrict__ pa,
                                               const float* __restrict__ row,
                                               const int* __restrict__ gstart,
                                               float* __restrict__ alive,
                                               float* __restrict__ rep){
    int g = blockIdx.x, tid = threadIdx.x;
    int w = tid >> 6, lane = tid & 63;
    int beg = gstart[g], end = gstart[g+1];
    const double tot = (double)NN * (double)HH;
    double m = stats[0] / tot;
    double var = stats[1] / tot - m*m;
    float mf = (float)m;
    float rs = rsqrtf((float)var + 1e-5f);
    float2 q0 = ((const float2*)p0)[lane];
    float2 q1 = ((const float2*)p1)[lane];
    float pa0 = pa[0], pa1 = pa[1], pa2 = pa[2];
    float csx = 0.f, csy = 0.f, cmx = -INFINITY, cmy = -INFINITY;
    for (int n = beg + w; n < end; n += 16){
        u32 hv = ((u32*)(hb + (size_t)n*HH))[lane];
        float vx = (bf2f((u16)(hv & 0xffffu)) - mf) * rs;
        float vy = (bf2f((u16)(hv >> 16))    - mf) * rs;
        float d0 = vx*q0.x + vy*q0.y;
        float d1 = vx*q1.x + vy*q1.y;
        #pragma unroll
        for (int o=32;o>0;o>>=1){ d0 += __shfl_xor(d0,o,64); d1 += __shfl_xor(d1,o,64); }
        float g1 = 1.f/(1.f + expf(-d0));
        float g2 = tanhf(d1);
        float gate = pa0*g1 + pa1*g2 + pa2;
        float keep = gate > THR ? 1.f : 0.f;
        float sc = gate*keep;
        vx *= sc; vy *= sc;
        ((u32*)(hb + (size_t)n*HH))[lane] = pack2(vx, vy);
        if (lane == 0 && keep == 0.f) alive[n] = 0.f;
        csx += vx; csy += vy;
        cmx = fmaxf(cmx, vx); cmy = fmaxf(cmy, vy);
    }
    __shared__ float ls[16][HH];
    __shared__ float lm[16][HH];
    ls[w][2*lane] = csx; ls[w][2*lane+1] = csy;
    lm[w][2*lane] = cmx; lm[w][2*lane+1] = cmy;
    __syncthreads();
    if (tid < HH){
        float s = 0.f, mx = -INFINITY;
        #pragma unroll
        for (int i=0;i<16;++i){ s += ls[i][tid]; mx = fmaxf(mx, lm[i][tid]); }
        if (mx == -INFINITY) mx = 0.f;
        float cnt = (float)(end - beg);
        float mean = s / fmaxf(cnt, 1.f);
        rep[(size_t)g*HH + tid] = row[0]*mean + row[1]*mx + row[2]*s;
    }
}

// standalone mixed readout (initial layer), 1024 threads = 8 row-stripes
__global__ __launch_bounds__(1024) void readout_k(const u16* __restrict__ h,
                                                  const int* __restrict__ gstart,
                                                  const float* __restrict__ w,
                                                  float* __restrict__ rep){
    int g = blockIdx.x;
    int t = threadIdx.x & 127, q = threadIdx.x >> 7;   // q in 0..7
    int beg = gstart[g], end = gstart[g+1];
    float sum = 0.f, mx = -INFINITY;
    for (int n = beg + q; n < end; n += 8){
        float v = bf2f(h[(size_t)n*HH + t]);
        sum += v;
        mx = fmaxf(mx, v);
    }
    __shared__ float ss[8][HH];
    __shared__ float ms[8][HH];
    ss[q][t] = sum; ms[q][t] = mx;
    __syncthreads();
    if (threadIdx.x < HH){
        float s = 0.f, m = -INFINITY;
        #pragma unroll
        for (int i=0;i<8;++i){ s += ss[i][threadIdx.x]; m = fmaxf(m, ms[i][threadIdx.x]); }
        if (m == -INFINITY) m = 0.f;
        float cnt = (float)(end - beg);
        float mean = s / fmaxf(cnt, 1.f);
        rep[(size_t)g*HH + threadIdx.x] = w[0]*mean + w[1]*m + w[2]*s;
    }
}

__global__ __launch_bounds__(128) void final_k(const float* __restrict__ reps,
                                               const float* __restrict__ la,
                                               const float* __restrict__ loW,
                                               const float* __restrict__ lob,
                                               const float* __restrict__ cW,
                                               const float* __restrict__ cb,
                                               float* __restrict__ out){
    int g = blockIdx.x, t = threadIdx.x;
    float r0 = reps[(size_t)(0*GG+g)*HH + t];
    float r1 = reps[(size_t)(1*GG+g)*HH + t];
    float r2 = reps[(size_t)(2*GG+g)*HH + t];
    float r3 = reps[(size_t)(3*GG+g)*HH + t];
    float s = r0+r1+r2+r3;
    float mean = 0.25f*s;
    float mx = fmaxf(fmaxf(r0,r1), fmaxf(r2,r3));
    float z = la[0]*elu_f(s) + la[1]*elu_f(mean) + la[2]*elu_f(mx);
    __shared__ float zs[HH];
    zs[t] = z;
    __syncthreads();
    float a = lob[t];
    for (int k=0;k<HH;++k) a = fmaf(zs[k], loW[(size_t)k*HH + t], a);
    float z2 = elu_f(a);
    __shared__ float z2s[HH];
    z2s[t] = z2;
    __syncthreads();
    __shared__ float lg[OUTC];
    if (t < OUTC){
        float acc = cb[t];
        for (int k=0;k<HH;++k) acc = fmaf(z2s[k], cW[(size_t)k*OUTC + t], acc);
        lg[t] = acc;
    }
    __syncthreads();
    if (t == 0){
        float m = lg[0];
        for (int o=1;o<OUTC;++o) m = fmaxf(m, lg[o]);
        float se = 0.f;
        for (int o=0;o<OUTC;++o) se += expf(lg[o]-m);
        float lse = m + logf(se);
        for (int o=0;o<OUTC;++o) out[(size_t)g*OUTC + o] = lg[o] - lse;
    }
}

// ---------------- host launch ----------------

extern "C" void kernel_launch(void* const* d_in, const int* in_sizes, int n_in,
                              void* d_out, int out_size, void* d_ws, size_t ws_size,
                              hipStream_t stream){
    const float* x     = (const float*)d_in[0];
    const int*   ei    = (const int*)d_in[1];
    const int*   batch = (const int*)d_in[2];
    const float* l1W   = (const float*)d_in[3];
    const float* l1b   = (const float*)d_in[4];
    const float* gW    = (const float*)d_in[5];
    const float* poolp = (const float*)d_in[6];
    const float* loW   = (const float*)d_in[7];
    const float* lob   = (const float*)d_in[8];
    const float* cW    = (const float*)d_in[9];
    const float* cb    = (const float*)d_in[10];
    const float* nalog = (const float*)d_in[11];
    const float* pllog = (const float*)d_in[12];
    const float* rolog = (const float*)d_in[13];
    const float* lalog = (const float*)d_in[14];
    float* out = (float*)d_out;

    char* wsb = (char*)d_ws;
    size_t off = 0;
    auto alloc = [&](size_t bytes)->char* {
        char* p = wsb + off;
        off += (bytes + 255) & ~(size_t)255;
        return p;
    };
    const int EEP = EE + 3*NN + 16;                 // padded CSR capacity
    u16*   hb     = (u16*)alloc(sizeof(u16)*(size_t)(NN+1)*HH);  // +1 sentinel row
    u16*   xb     = (u16*)alloc(sizeof(u16)*(size_t)NN*HH);
    u16*   sagg   = (u16*)alloc(sizeof(u16)*(size_t)NN*HH);
    u16*   gagg   = (u16*)alloc(sizeof(u16)*(size_t)NN*HH);
    u16*   Wc     = (u16*)alloc(sizeof(u16)*(size_t)LL*4*HH*HH);
    u16*   lin1t  = (u16*)alloc(sizeof(u16)*HH*HH);
    int*   row_ptr= (int*)alloc(sizeof(int)*(NN+1));
    int*   counts = (int*)alloc(sizeof(int)*NN);
    int*   cursor = (int*)alloc(sizeof(int)*NN);
    int*   pre    = (int*)alloc(sizeof(int)*NN);
    int*   bsum   = (int*)alloc(sizeof(int)*64);
    int*   csr_src= (int*)alloc(sizeof(int)*EEP);
    float2* ar2   = (float2*)alloc(sizeof(float2)*(NN+1));       // +1 sentinel
    float* invdeg = (float*)alloc(sizeof(float)*NN);
    float* alive  = (float*)alloc(sizeof(float)*(NN+1));         // +1 sentinel
    int*   gstart = (int*)alloc(sizeof(int)*(GG+1));
    float* reps   = (float*)alloc(sizeof(float)*(size_t)(LL+1)*GG*HH);
    float* coef   = (float*)alloc(sizeof(float)*64);
    double* stats = (double*)alloc(sizeof(double)*2*LL);

    const int* srcp = ei;
    const int* dstp = ei + EE;

    hipMemsetAsync(counts, 0, sizeof(int)*NN, stream);
    hipMemsetAsync(stats, 0, sizeof(double)*2*LL, stream);

    const int SCAN_BLOCKS = (NN + 1023)/1024;   // 49

    prep_coef_k<<<1, 64, 0, stream>>>(nalog, pllog, rolog, lalog, coef);
    prep_w_k<<<(LL*4*16384 + 16384 + 255)/256, 256, 0, stream>>>(gW, l1W, coef, Wc, lin1t);
    count_k<<<(EE + 255)/256, 256, 0, stream>>>(dstp, counts);
    scan1_k<<<SCAN_BLOCKS, 256, 0, stream>>>(counts, pre, bsum);
    scan3_k<<<SCAN_BLOCKS, 256, 0, stream>>>(pre, bsum, row_ptr, cursor);
    fill_k<<<(EE + 255)/256, 256, 0, stream>>>(srcp, dstp, cursor, csr_src);
    pad_fill_k<<<(NN + 255)/256, 256, 0, stream>>>(cursor, row_ptr, csr_src);
    gstart_k<<<(GG + 256)/256, 256, 0, stream>>>(batch, gstart);
    init_alive_k<<<(NN + 256)/256, 256, 0, stream>>>(alive);
    x2bf_k<<<(NN*HH/8 + 255)/256, 256, 0, stream>>>(x, xb);

    const int gemm_blocks = (NN + 127)/128;   // 128-row tiles -> 391 blocks

    // h = elu(x @ lin1_W + b) -> bf16
    mm_k<2,1><<<gemm_blocks, 512, 0, stream>>>(xb, nullptr, nullptr, nullptr,
                                               lin1t, nullptr, l1b, hb, nullptr, NN);
    readout_k<<<GG, 1024, 0, stream>>>(hb, gstart, coef + 21, reps);

    for (int i=0;i<LL;++i){
        deg2_k<<<(NN + 3)/4, 256, 0, stream>>>(row_ptr, csr_src, alive, ar2, invdeg);
        agg_k<<<NN, 64, 0, stream>>>(hb, row_ptr, csr_src, ar2, sagg, gagg);
        mm_k<1,4><<<gemm_blocks, 512, 0, stream>>>(hb, sagg, sagg, gagg,
                                                   Wc + (size_t)i*4*16384, invdeg, nullptr,
                                                   hb, stats + 2*i, NN);
        lnro_k<<<GG, 1024, 0, stream>>>(hb, stats + 2*i,
                                        poolp + (size_t)(i*2+0)*HH,
                                        poolp + (size_t)(i*2+1)*HH,
                                        coef + 12 + i*3,
                                        coef + 21 + (i+1)*3,
                                        gstart, alive,
                                        reps + (size_t)(i+1)*GG*HH);
    }

    final_k<<<GG, HH, 0, stream>>>(reps, coef + 33, loW, lob, cW, cb, out);
}